// Round 1
// baseline (293.995 us; speedup 1.0000x reference)
//
#include <hip/hip_runtime.h>
#include <stdint.h>
#include <stddef.h>

typedef __bf16 bf16;
typedef __bf16 bf16x8 __attribute__((ext_vector_type(8)));
typedef float  f32x4  __attribute__((ext_vector_type(4)));

typedef __attribute__((address_space(3))) void       lds_void;
typedef __attribute__((address_space(1))) const void gbl_cvoid;

#define ASYNC_CP16(g, l) \
  __builtin_amdgcn_global_load_lds((gbl_cvoid*)(g), (lds_void*)(l), 16, 0, 0)

// chunk swizzle: spreads b128 fragment reads across banks (verified round 5)
__device__ __forceinline__ int swz(int r) { return (r & 7) ^ ((r & 8) >> 1); }

// ---------------------------------------------------------------------------
// Prep kernel: blocks [0,65536) pack adjacency(+I) into 64-bit masks;
// blocks [65536, ...) do the batched fp32->bf16 cast.
// ---------------------------------------------------------------------------
struct CastArgs {
  const float* src[7];
  bf16*        dst[7];
  int          cum[8];
};

__global__ __launch_bounds__(256) void k_prep(
    const int* __restrict__ adj, unsigned long long* __restrict__ mb,
    CastArgs a, int total8)
{
  const int bid = blockIdx.x;
  if (bid < 65536) {
    const int gw   = (int)(((unsigned)bid * 256 + threadIdx.x) >> 6);
    const int lane = threadIdx.x & 63;
    const int av   = adj[(size_t)gw * 64 + lane];
    unsigned long long m = __ballot(av != 0);
    const int row = gw >> 6, wc = gw & 63;
    if ((row >> 6) == wc) m |= 1ull << (row & 63);
    if (lane == 0) mb[gw] = m;
  } else {
    const int g = (bid - 65536) * 256 + threadIdx.x;
    if (g >= total8) return;
    int t = 0;
    while (a.cum[t + 1] <= g) ++t;
    const int i = g - a.cum[t];
    const float4* s = (const float4*)(a.src[t]) + (size_t)i * 2;
    const float4 x0 = s[0], x1 = s[1];
    bf16x8 y;
    y[0] = (bf16)x0.x; y[1] = (bf16)x0.y; y[2] = (bf16)x0.z; y[3] = (bf16)x0.w;
    y[4] = (bf16)x1.x; y[5] = (bf16)x1.y; y[6] = (bf16)x1.z; y[7] = (bf16)x1.w;
    *(bf16x8*)(a.dst[t] + (size_t)i * 8) = y;
  }
}

// ---------------------------------------------------------------------------
// Async-staged GEMM core, templated on m-tile (MT=128: 2x2 waves, 4x4 frags;
// MT=64: 1x4 waves, 4x2 frags). N-tile fixed 128, BK=64.
// ---------------------------------------------------------------------------
template <int MT>
__device__ __forceinline__ void gemm_core_async(
    const bf16* __restrict__ A, const bf16* __restrict__ B,
    bf16* As, bf16* Bs, f32x4 (&acc)[4][(MT == 128) ? 4 : 2],
    int K, int m0, int n0, int kbeg, int kend)
{
  constexpr int FN = (MT == 128) ? 4 : 2;
  constexpr int IA = MT / 32;             // A staging wave-instrs per wave
  const int tid    = threadIdx.x;
  const int lane   = tid & 63;
  const int wave   = tid >> 6;
  const int lane15 = lane & 15;
  const int quad   = lane >> 4;
  const int wm     = (MT == 128) ? ((wave & 1) << 6) : 0;
  const int wn     = (MT == 128) ? ((wave >> 1) << 6) : (wave << 5);

  int srA[IA], soA[IA], srB[4], soB[4];
#pragma unroll
  for (int i = 0; i < IA; ++i) {
    int c  = ((wave * IA + i) << 6) + lane;
    srA[i] = c >> 3;
    soA[i] = ((c & 7) ^ swz(srA[i])) * 8;
  }
#pragma unroll
  for (int i = 0; i < 4; ++i) {
    int c  = ((wave * 4 + i) << 6) + lane;
    srB[i] = c >> 3;
    soB[i] = ((c & 7) ^ swz(srB[i])) * 8;
  }

  const bf16* Ab = A + (size_t)m0 * K;
  const bf16* Bb = B + (size_t)n0 * K;

  for (int k0 = kbeg; k0 < kend; k0 += 64) {
#pragma unroll
    for (int i = 0; i < IA; ++i)
      ASYNC_CP16(Ab + (size_t)srA[i] * K + k0 + soA[i], &As[(wave * IA + i) * 512]);
#pragma unroll
    for (int i = 0; i < 4; ++i)
      ASYNC_CP16(Bb + (size_t)srB[i] * K + k0 + soB[i], &Bs[(wave * 4 + i) * 512]);
    __syncthreads();

#pragma unroll
    for (int kk = 0; kk < 2; ++kk) {
      bf16x8 af[4], bfr[FN];
#pragma unroll
      for (int f = 0; f < 4; ++f) {
        const int ra = wm + f * 16 + lane15;
        af[f] = *(const bf16x8*)&As[ra * 64 + (((kk * 4 + quad) ^ swz(ra)) * 8)];
      }
#pragma unroll
      for (int f = 0; f < FN; ++f) {
        const int rb = wn + f * 16 + lane15;
        bfr[f] = *(const bf16x8*)&Bs[rb * 64 + (((kk * 4 + quad) ^ swz(rb)) * 8)];
      }
#pragma unroll
      for (int fm = 0; fm < 4; ++fm)
#pragma unroll
        for (int fn = 0; fn < FN; ++fn)
          acc[fm][fn] = __builtin_amdgcn_mfma_f32_16x16x32_bf16(
              af[fm], bfr[fn], acc[fm][fn], 0, 0, 0);
    }
    __syncthreads();
  }
}

// FF1: MT=128 full-K GEMM + bias + relu.
__global__ __launch_bounds__(256, 2) void k_gemm(
    const bf16* __restrict__ A, const bf16* __restrict__ B,
    const float* __restrict__ bias, bf16* __restrict__ C,
    int N, int K, int relu)
{
  __shared__ __align__(16) bf16 As[128 * 64];
  __shared__ __align__(16) bf16 Bs[128 * 64];
  const int m0 = blockIdx.x * 128, n0 = blockIdx.y * 128;
  f32x4 acc[4][4] = {};
  gemm_core_async<128>(A, B, As, Bs, acc, K, m0, n0, 0, K);

  const int lane15 = threadIdx.x & 15;
  const int quad   = (threadIdx.x & 63) >> 4;
  const int wave   = threadIdx.x >> 6;
  const int wm = (wave & 1) << 6, wn = (wave >> 1) << 6;
#pragma unroll
  for (int fm = 0; fm < 4; ++fm)
#pragma unroll
    for (int fn = 0; fn < 4; ++fn) {
      const int col = n0 + wn + fn * 16 + lane15;
      const float bv = bias[col];
#pragma unroll
      for (int r = 0; r < 4; ++r) {
        const int row = m0 + wm + fm * 16 + quad * 4 + r;
        float v = acc[fm][fn][r] + bv;
        if (relu) v = fmaxf(v, 0.0f);
        C[(size_t)row * N + col] = (bf16)v;
      }
    }
}

// QKV: one GEMM over concat weights [1536,512] (rows 0-511 Wq, 512-1023 Wk,
// 1024-1535 Wv). MT=64 -> grid (64,12) = 768 blocks. V-projection blocks
// write vt (transposed) via an LDS transpose in the epilogue.
__global__ __launch_bounds__(256, 4) void k_gemm_qkv(
    const bf16* __restrict__ h, const bf16* __restrict__ Wcat,
    const float* __restrict__ bq, const float* __restrict__ bk,
    const float* __restrict__ bv,
    bf16* __restrict__ q, bf16* __restrict__ k, bf16* __restrict__ vt)
{
  __shared__ __align__(16) bf16 SM[64 * 64 + 128 * 64];   // 24 KB
  bf16* As = SM;
  bf16* Bs = SM + 64 * 64;
  const int m0 = blockIdx.x * 64, n0 = blockIdx.y * 128;
  f32x4 acc[4][2] = {};
  gemm_core_async<64>(h, Wcat, As, Bs, acc, 512, m0, n0, 0, 512);

  const int lane15 = threadIdx.x & 15;
  const int quad   = (threadIdx.x & 63) >> 4;
  const int wave   = threadIdx.x >> 6;
  const int wn     = wave << 5;
  const int proj   = n0 >> 9;                  // 0=q 1=k 2=v
  const int ncol0  = n0 & 511;
  const float* bias = (proj == 0) ? bq : (proj == 1) ? bk : bv;

  if (proj < 2) {
    bf16* C = proj ? k : q;
#pragma unroll
    for (int fm = 0; fm < 4; ++fm)
#pragma unroll
      for (int fn = 0; fn < 2; ++fn) {
        const int col = ncol0 + wn + fn * 16 + lane15;
        const float bvv = bias[col];
#pragma unroll
        for (int r = 0; r < 4; ++r) {
          const int row = m0 + fm * 16 + quad * 4 + r;
          C[(size_t)row * 512 + col] = (bf16)(acc[fm][fn][r] + bvv);
        }
      }
  } else {
    // transpose 64(tokens) x 128(vdims) through LDS -> vt[vdim][token]
    __syncthreads();   // K-loop LDS dead
#pragma unroll
    for (int fm = 0; fm < 4; ++fm)
#pragma unroll
      for (int fn = 0; fn < 2; ++fn) {
        const int colL = wn + fn * 16 + lane15;
        const float bvv = bias[ncol0 + colL];
#pragma unroll
        for (int r = 0; r < 4; ++r) {
          const int rowL = fm * 16 + quad * 4 + r;
          SM[colL * 72 + rowL] = (bf16)(acc[fm][fn][r] + bvv);
        }
      }
    __syncthreads();
#pragma unroll
    for (int i = 0; i < 4; ++i) {
      const int c = i * 256 + threadIdx.x;     // 1024 chunks
      const int colL = c >> 3, rw = (c & 7) * 8;
      *(bf16x8*)&vt[(size_t)(ncol0 + colL) * 4096 + m0 + rw] =
          *(const bf16x8*)&SM[colL * 72 + rw];
    }
  }
}

// Split-K GEMM (MT=64) -> f32 partials Cp[z][4096][N].
__global__ __launch_bounds__(256, 4) void k_gemm_sk(
    const bf16* __restrict__ A, const bf16* __restrict__ B,
    float* __restrict__ Cp, int N, int K, int Ksplit)
{
  __shared__ __align__(16) bf16 As[64 * 64];
  __shared__ __align__(16) bf16 Bs[128 * 64];
  const int m0 = blockIdx.x * 64, n0 = blockIdx.y * 128;
  const int kbeg = blockIdx.z * Ksplit;
  f32x4 acc[4][2] = {};
  gemm_core_async<64>(A, B, As, Bs, acc, K, m0, n0, kbeg, kbeg + Ksplit);

  const int lane15 = threadIdx.x & 15;
  const int quad   = (threadIdx.x & 63) >> 4;
  const int wave   = threadIdx.x >> 6;
  const int wn     = wave << 5;
  float* Cz = Cp + (size_t)blockIdx.z * 4096 * N;
#pragma unroll
  for (int fm = 0; fm < 4; ++fm)
#pragma unroll
    for (int fn = 0; fn < 2; ++fn) {
      const int col = n0 + wn + fn * 16 + lane15;
#pragma unroll
      for (int r = 0; r < 4; ++r) {
        const int row = m0 + fm * 16 + quad * 4 + r;
        Cz[(size_t)row * N + col] = acc[fm][fn][r];
      }
    }
}

// ---------------------------------------------------------------------------
// Flash attention, split-K x4, 32 q-rows/wave, async K/V staging (swizzled,
// no pad). No online max (bounded scores); l via ones-MFMA; P round-trips
// LDS bf16 (wave-private).
//
// R1 changes vs baseline:
//  * issue-early/drain-late staging: V(t) issued at top of QK phase, K(t+1)
//    issued at top of PV phase -> every global_load_lds gets a full compute
//    phase of flight before the barrier's vmcnt(0) drain (was: issue
//    immediately followed by drain = full latency exposed per k-tile).
//  * P-buffer pitch 72 -> 68 elements (34 dw): quad row-stride 136 dw = 8
//    mod 32, so the 32 scalar b16 P-writes land 2 lanes/bank (free) instead
//    of 4-way aliased; b128 P-reads stay at the uniform 8 dw/bank minimum.
//  * s_setprio(1) around QK / PV MFMA clusters (T5).
// ---------------------------------------------------------------------------
__global__ __launch_bounds__(256, 4) void k_attn(
    const bf16* __restrict__ Q, const bf16* __restrict__ Km,
    const bf16* __restrict__ Vt, const unsigned long long* __restrict__ mb,
    bf16* __restrict__ Opart, float* __restrict__ Lpart)
{
  constexpr int PP = 68;                       // P pitch (elements)
  __shared__ __align__(16) bf16 Ks[64 * 64];
  __shared__ __align__(16) bf16 Vs[64 * 64];
  __shared__ __align__(16) bf16 Plb[4][32 * PP];

  const int tid    = threadIdx.x;
  const int wave   = tid >> 6;
  const int lane   = tid & 63;
  const int lane15 = lane & 15;
  const int quad   = lane >> 4;
  const int sp     = blockIdx.x & 3;
  const int hd     = (blockIdx.x >> 2) & 7;
  const int qt     = blockIdx.x >> 5;
  const int qrow   = qt * 128 + wave * 32;

  bf16x8 qf[2][2];
#pragma unroll
  for (int mt = 0; mt < 2; ++mt)
#pragma unroll
    for (int c = 0; c < 2; ++c)
      qf[mt][c] = *(const bf16x8*)&Q[(size_t)(qrow + mt * 16 + lane15) * 512 +
                                     hd * 64 + c * 32 + quad * 8];

  // async staging bases (chunk geometry identical to GEMM core, 2 instrs/wave)
  int srK[2], soK[2];
#pragma unroll
  for (int i = 0; i < 2; ++i) {
    int c  = ((wave * 2 + i) << 6) + lane;
    srK[i] = c >> 3;
    soK[i] = ((c & 7) ^ swz(srK[i])) * 8;
  }
  const bf16* KmB[2] = {
      Km + (size_t)srK[0] * 512 + hd * 64 + soK[0],
      Km + (size_t)srK[1] * 512 + hd * 64 + soK[1]};
  const bf16* VtB[2] = {
      Vt + (size_t)(hd * 64 + srK[0]) * 4096 + soK[0],
      Vt + (size_t)(hd * 64 + srK[1]) * 4096 + soK[1]};

  bf16x8 ones;
#pragma unroll
  for (int j = 0; j < 8; ++j) ones[j] = (bf16)1.0f;

  f32x4 o[2][4] = {};
  f32x4 la[2]   = {};

  const int kt0 = sp * 16;
  // prologue: stage K(kt0); one exposed drain (per block, not per tile)
#pragma unroll
  for (int i = 0; i < 2; ++i)
    ASYNC_CP16(KmB[i] + (size_t)(kt0 * 64) * 512, &Ks[(wave * 2 + i) * 512]);
  __syncthreads();

  for (int kt = kt0; kt < kt0 + 16; ++kt) {
    const int kb = kt * 64;

    // ---- Phase A: QK^T from Ks (ready); V(kt) in flight underneath ----
#pragma unroll
    for (int i = 0; i < 2; ++i)
      ASYNC_CP16(VtB[i] + kb, &Vs[(wave * 2 + i) * 512]);

    unsigned long long mw[2][4];
#pragma unroll
    for (int mt = 0; mt < 2; ++mt)
#pragma unroll
      for (int r = 0; r < 4; ++r)
        mw[mt][r] = mb[(size_t)(qrow + mt * 16 + quad * 4 + r) * 64 + kt] >> lane15;

#pragma unroll
    for (int g = 0; g < 4; ++g) {
      const int row = g * 16 + lane15;
      bf16x8 k0f = *(const bf16x8*)&Ks[row * 64 + ((quad       ^ swz(row)) * 8)];
      bf16x8 k1f = *(const bf16x8*)&Ks[row * 64 + (((4 + quad) ^ swz(row)) * 8)];
#pragma unroll
      for (int mt = 0; mt < 2; ++mt) {
        f32x4 s = {};
        __builtin_amdgcn_s_setprio(1);
        s = __builtin_amdgcn_mfma_f32_16x16x32_bf16(qf[mt][0], k0f, s, 0, 0, 0);
        s = __builtin_amdgcn_mfma_f32_16x16x32_bf16(qf[mt][1], k1f, s, 0, 0, 0);
        __builtin_amdgcn_s_setprio(0);
#pragma unroll
        for (int r = 0; r < 4; ++r) {
          const bool ok = ((mw[mt][r] >> (g * 16)) & 1ull) != 0;
          const float p = ok ? __expf(s[r] * 0.125f) : 0.0f;
          Plb[wave][(mt * 16 + quad * 4 + r) * PP + g * 16 + lane15] = (bf16)p;
        }
      }
    }
    __syncthreads();   // drains V(kt) (hidden under QK); Plb visible

    // ---- Phase B: PV from Vs; K(kt+1) in flight underneath ----
    if (kt + 1 < kt0 + 16) {
      const int kb2 = (kt + 1) * 64;
#pragma unroll
      for (int i = 0; i < 2; ++i)
        ASYNC_CP16(KmB[i] + (size_t)kb2 * 512, &Ks[(wave * 2 + i) * 512]);
    }

#pragma unroll
    for (int c2 = 0; c2 < 2; ++c2) {
      bf16x8 vf[4];
#pragma unroll
      for (int g2 = 0; g2 < 4; ++g2) {
        const int row = g2 * 16 + lane15;
        vf[g2] = *(const bf16x8*)&Vs[row * 64 + (((c2 * 4 + quad) ^ swz(row)) * 8)];
      }
#pragma unroll
      for (int mt = 0; mt < 2; ++mt) {
        bf16x8 pa = *(const bf16x8*)&Plb[wave][(mt * 16 + lane15) * PP + c2 * 32 + quad * 8];
        __builtin_amdgcn_s_setprio(1);
        la[mt] = __builtin_amdgcn_mfma_f32_16x16x32_bf16(pa, ones, la[mt], 0, 0, 0);
#pragma unroll
        for (int g2 = 0; g2 < 4; ++g2)
          o[mt][g2] = __builtin_amdgcn_mfma_f32_16x16x32_bf16(pa, vf[g2], o[mt][g2], 0, 0, 0);
        __builtin_amdgcn_s_setprio(0);
      }
    }
    __syncthreads();   // drains K(kt+1) (hidden under PV); Vs/Plb reusable
  }

  bf16* Oz = Opart + (size_t)sp * 4096 * 512;
#pragma unroll
  for (int mt = 0; mt < 2; ++mt) {
#pragma unroll
    for (int g2 = 0; g2 < 4; ++g2)
#pragma unroll
      for (int r = 0; r < 4; ++r) {
        const int row = qrow + mt * 16 + quad * 4 + r;
        Oz[(size_t)row * 512 + hd * 64 + g2 * 16 + lane15] = (bf16)o[mt][g2][r];
      }
    if (lane15 == 0) {
#pragma unroll
      for (int r = 0; r < 4; ++r)
        Lpart[sp * 32768 + (qrow + mt * 16 + quad * 4 + r) * 8 + hd] = la[mt][r];
    }
  }
}

// Combine attention partials: ctx = (sum_s O_s) / (sum_s l_s).
__global__ __launch_bounds__(256) void k_attn_combine(
    const bf16* __restrict__ Opart, const float* __restrict__ Lpart,
    bf16* __restrict__ ctx)
{
  const int g = blockIdx.x * 256 + threadIdx.x;
  const size_t base = (size_t)g * 8;
  const int row = g >> 6;
  const int hd  = (g & 63) >> 3;
  float acc[8] = {};
  float l = 0.0f;
#pragma unroll
  for (int s = 0; s < 4; ++s) {
    bf16x8 ov = *(const bf16x8*)&Opart[(size_t)s * 4096 * 512 + base];
#pragma unroll
    for (int j = 0; j < 8; ++j) acc[j] += (float)ov[j];
    l += Lpart[s * 32768 + row * 8 + hd];
  }
  const float rl = 1.0f / l;
  bf16x8 y;
#pragma unroll
  for (int j = 0; j < 8; ++j) y[j] = (bf16)(acc[j] * rl);
  *(bf16x8*)(ctx + base) = y;
}

// ---------------------------------------------------------------------------
// Fused: split-K combine + bias + residual + LayerNorm. N=512 fixed.
// ---------------------------------------------------------------------------
template <int F32OUT>
__global__ __launch_bounds__(256) void k_addln_sk(
    const bf16* __restrict__ x, const float* __restrict__ Cp,
    const float* __restrict__ bias,
    const float* __restrict__ gam, const float* __restrict__ bet,
    void* __restrict__ out)
{
  const int wave = threadIdx.x >> 6, lane = threadIdx.x & 63;
  const int row  = blockIdx.x * 4 + wave;
  const size_t base = (size_t)row * 512 + lane * 8;
  const int col = lane * 8;
  bf16x8 xv = *(const bf16x8*)(x + base);
  const float* p0 = Cp + base;
  const float* p1 = Cp + (size_t)4096 * 512 + base;
  f32x4 a0 = *(const f32x4*)p0, a1 = *(const f32x4*)(p0 + 4);
  f32x4 b0 = *(const f32x4*)p1, b1 = *(const f32x4*)(p1 + 4);
  f32x4 c0 = *(const f32x4*)(bias + col), c1 = *(const f32x4*)(bias + col + 4);
  float v[8], s = 0.0f, s2 = 0.0f;
#pragma unroll
  for (int j = 0; j < 4; ++j) {
    v[j]     = (float)xv[j]     + a0[j] + b0[j] + c0[j];
    v[4 + j] = (float)xv[4 + j] + a1[j] + b1[j] + c1[j];
  }
#pragma unroll
  for (int j = 0; j < 8; ++j) { s += v[j]; s2 += v[j] * v[j]; }
#pragma unroll
  for (int d = 1; d < 64; d <<= 1) { s += __shfl_xor(s, d, 64); s2 += __shfl_xor(s2, d, 64); }
  const float mu  = s * (1.0f / 512.0f);
  const float var = s2 * (1.0f / 512.0f) - mu * mu;
  const float rs  = rsqrtf(var + 1e-5f);
  f32x4 g0 = *(const f32x4*)(gam + col), g1 = *(const f32x4*)(gam + col + 4);
  f32x4 e0 = *(const f32x4*)(bet + col), e1 = *(const f32x4*)(bet + col + 4);
  if (F32OUT) {
    float* o = (float*)out + base;
#pragma unroll
    for (int j = 0; j < 4; ++j) {
      o[j]     = ((v[j] - mu) * rs) * g0[j] + e0[j];
      o[4 + j] = ((v[4 + j] - mu) * rs) * g1[j] + e1[j];
    }
  } else {
    bf16x8 ov;
#pragma unroll
    for (int j = 0; j < 4; ++j) {
      ov[j]     = (bf16)(((v[j] - mu) * rs) * g0[j] + e0[j]);
      ov[4 + j] = (bf16)(((v[4 + j] - mu) * rs) * g1[j] + e1[j]);
    }
    *(bf16x8*)((bf16*)out + base) = ov;
  }
}

// ---------------------------------------------------------------------------
extern "C" void kernel_launch(void* const* d_in, const int* in_sizes, int n_in,
                              void* d_out, int out_size, void* d_ws, size_t ws_size,
                              hipStream_t stream)
{
  const int*   adj = (const int*)  d_in[1];
  const float* bq  = (const float*)d_in[3];
  const float* bk  = (const float*)d_in[5];
  const float* bv  = (const float*)d_in[7];
  const float* bo  = (const float*)d_in[9];
  const float* b1  = (const float*)d_in[11];
  const float* b2  = (const float*)d_in[13];
  const float* g1  = (const float*)d_in[14];
  const float* be1 = (const float*)d_in[15];
  const float* g2  = (const float*)d_in[16];
  const float* be2 = (const float*)d_in[17];

  char* ws = (char*)d_ws;
  const size_t MB = 1024 * 1024;

  // bf16 arena. Wq/Wk/Wv are contiguous, forming the concat [1536,512] matrix.
  bf16* hb  = (bf16*)(ws + 0 * MB);                  // 4 MB
  bf16* Wqb = (bf16*)(ws + 4 * MB);                  // concat base
  bf16* Wkb = (bf16*)(ws + 4 * MB + 512 * 1024);
  bf16* Wvb = (bf16*)(ws + 5 * MB);
  bf16* Wob = (bf16*)(ws + 5 * MB + 512 * 1024);
  bf16* W1b = (bf16*)(ws + 6 * MB);                  // 2 MB
  bf16* W2b = (bf16*)(ws + 8 * MB);                  // 2 MB

  // intermediates (lifetime-packed)
  bf16* q    = (bf16*)(ws + 12 * MB);   // dead after attn
  bf16* k    = (bf16*)(ws + 16 * MB);   // dead after attn
  bf16* vt   = (bf16*)(ws + 24 * MB);   // dead after attn
  unsigned long long* mbits = (unsigned long long*)(ws + 28 * MB); // 2 MB
  bf16* ctx  = (bf16*)(ws + 30 * MB);   // dead after Wo sk-gemm
  bf16*  Opart = (bf16*)(ws + 34 * MB); // 16 MB, dead after attn_combine
  float* Lpart = (float*)(ws + 50 * MB);// 0.5 MB
  float* skP   = (float*)(ws + 34 * MB);// 16 MB f32 partials (over Opart)
  bf16* h1   = (bf16*)(ws + 12 * MB);   // over q (dead)
  bf16* ff1  = (bf16*)(ws + 16 * MB);   // 16 MB over k,vt,mbits,ctx (all dead)

  // cast args
  CastArgs ca;
  const int srcIdx[7] = {0, 2, 4, 6, 8, 10, 12};
  bf16* dsts[7] = {hb, Wqb, Wkb, Wvb, Wob, W1b, W2b};
  int cum = 0;
  for (int t = 0; t < 7; ++t) {
    ca.src[t] = (const float*)d_in[srcIdx[t]];
    ca.dst[t] = dsts[t];
    ca.cum[t] = cum;
    cum += in_sizes[srcIdx[t]] / 8;
  }
  ca.cum[7] = cum;

  const dim3 blk(256);

  // 1. prep: packmask (65536 blocks) + cast
  k_prep<<<dim3(65536 + (cum + 255) / 256), blk, 0, stream>>>(adj, mbits, ca, cum);
  // 2. fused QKV (768 blocks); V blocks write vt directly
  k_gemm_qkv<<<dim3(64, 12), blk, 0, stream>>>(hb, Wqb, bq, bk, bv, q, k, vt);
  // 3. flash attention, split-K x4 (1024 blocks) + combine
  k_attn<<<dim3(1024), blk, 0, stream>>>(q, k, vt, mbits, Opart, Lpart);
  k_attn_combine<<<dim3(1024), blk, 0, stream>>>(Opart, Lpart, ctx);
  // 4. output projection split-K x2 (512 blocks) -> fused combine+LN1 -> h1
  k_gemm_sk<<<dim3(64, 4, 2), blk, 0, stream>>>(ctx, Wob, skP, 512, 512, 256);
  k_addln_sk<0><<<dim3(1024), blk, 0, stream>>>(hb, skP, bo, g1, be1, (void*)h1);
  // 5. ff1 = relu(h1 @ W1^T + b1)  (512 blocks)
  k_gemm<<<dim3(32, 16), blk, 0, stream>>>(h1, W1b, b1, ff1, 2048, 512, 1);
  // 6. ff2 split-K x2 (512 blocks) -> fused combine+LN2 -> d_out (fp32)
  k_gemm_sk<<<dim3(64, 4, 2), blk, 0, stream>>>(ff1, W2b, skP, 512, 2048, 1024);
  k_addln_sk<1><<<dim3(1024), blk, 0, stream>>>(h1, skP, b2, g2, be2, d_out);
}